// Round 1
// baseline (94.355 us; speedup 1.0000x reference)
//
#include <hip/hip_runtime.h>

// N=8192 rows, D=1024 cols, fp32.
// Row-wise cosine similarity -> MSE vs labels -> scalar mean.
// Memory-bound: 2*8192*1024*4B = 64 MiB read once.

#define NROWS 8192
#define DCOLS 1024
#define F4_PER_ROW (DCOLS / 4)   // 256 float4 per row
#define WAVES_PER_BLOCK 4
#define ROWS_PER_BLOCK WAVES_PER_BLOCK
#define NBLOCKS (NROWS / ROWS_PER_BLOCK)  // 2048

__global__ __launch_bounds__(256) void cos_mse_partial(
    const float4* __restrict__ A, const float4* __restrict__ B,
    const float* __restrict__ labels, float* __restrict__ partial) {
  const int lane = threadIdx.x & 63;
  const int wave = threadIdx.x >> 6;
  const int row  = blockIdx.x * ROWS_PER_BLOCK + wave;

  const float4* a = A + (size_t)row * F4_PER_ROW;
  const float4* b = B + (size_t)row * F4_PER_ROW;

  float dot = 0.f, na = 0.f, nb = 0.f;
#pragma unroll
  for (int j = 0; j < F4_PER_ROW / 64; ++j) {   // 4 iterations
    float4 av = a[lane + j * 64];
    float4 bv = b[lane + j * 64];
    dot += av.x * bv.x + av.y * bv.y + av.z * bv.z + av.w * bv.w;
    na  += av.x * av.x + av.y * av.y + av.z * av.z + av.w * av.w;
    nb  += bv.x * bv.x + bv.y * bv.y + bv.z * bv.z + bv.w * bv.w;
  }

  // 64-lane butterfly reduction
#pragma unroll
  for (int off = 32; off >= 1; off >>= 1) {
    dot += __shfl_xor(dot, off, 64);
    na  += __shfl_xor(na,  off, 64);
    nb  += __shfl_xor(nb,  off, 64);
  }

  __shared__ float s[WAVES_PER_BLOCK];
  if (lane == 0) {
    float score = dot * rsqrtf(na * nb);
    float e = score - labels[row];
    s[wave] = e * e;
  }
  __syncthreads();
  if (threadIdx.x == 0) {
    float acc = 0.f;
#pragma unroll
    for (int w = 0; w < WAVES_PER_BLOCK; ++w) acc += s[w];
    partial[blockIdx.x] = acc;
  }
}

__global__ __launch_bounds__(256) void reduce_partials(
    const float* __restrict__ partial, float* __restrict__ out) {
  // NBLOCKS = 2048 partials, one block of 256 threads.
  float acc = 0.f;
  for (int i = threadIdx.x; i < NBLOCKS; i += 256) acc += partial[i];
#pragma unroll
  for (int off = 32; off >= 1; off >>= 1) acc += __shfl_xor(acc, off, 64);

  __shared__ float s[4];
  const int lane = threadIdx.x & 63;
  const int wave = threadIdx.x >> 6;
  if (lane == 0) s[wave] = acc;
  __syncthreads();
  if (threadIdx.x == 0) {
    float total = s[0] + s[1] + s[2] + s[3];
    out[0] = total * (1.0f / (float)NROWS);
  }
}

extern "C" void kernel_launch(void* const* d_in, const int* in_sizes, int n_in,
                              void* d_out, int out_size, void* d_ws, size_t ws_size,
                              hipStream_t stream) {
  const float4* A = (const float4*)d_in[0];
  const float4* B = (const float4*)d_in[1];
  const float*  L = (const float*)d_in[2];
  float* partial = (float*)d_ws;   // NBLOCKS floats = 8 KiB
  float* out = (float*)d_out;

  cos_mse_partial<<<NBLOCKS, 256, 0, stream>>>(A, B, L, partial);
  reduce_partials<<<1, 256, 0, stream>>>(partial, out);
}